// Round 10
// baseline (516.215 us; speedup 1.0000x reference)
//
#include <hip/hip_runtime.h>
#include <hip/hip_bf16.h>

// PhraseDecoderLayer: B=4,S=1024,D=1024,H=16,HD=64,DFF=4096,MEM=256.
// Round 19: gemm128 chunk-XOR LDS swizzle (both-sides, rule 21).
// Round-18 post-mortem: gemm128 family tops the profile (ffn2 61.2us);
// per-step tally shows 48 ds_read_b128 x 12cy + 192 conflict-cy ~= the whole
// 1147cy step -- LDS-conflict-bound. [128][32] rows are 64B -> quad reads hit
// 2 banks (8-way). Fix: swizzle the 16B chunk within each row: key=(row>>1)&3;
// stage fetches global chunk (tid&3)^key into the LINEAR DMA slot (dest
// unchanged); reads use physical chunk quad^key (key=(m16>>1)&3, lane-uniform).
// Bank map: 2 lanes per 4-bank slot = free. Structure/schedule unchanged.
// gemm256/attn/gemm_bt/LN/canon unchanged from passing rounds.

using bf16 = __hip_bfloat16;
typedef __bf16 bf16x8 __attribute__((ext_vector_type(8)));
typedef float f32x4 __attribute__((ext_vector_type(4)));

static constexpr int Bn = 4, Ssz = 1024, Dm = 1024, Hh = 16, HDd = 64, DFFn = 4096, MEMn = 256;

__device__ inline float bf2f(bf16 x) { return __bfloat162float(x); }
__device__ inline bf16 f2bf(float x) { return __float2bfloat16(x); }

// async global->LDS, 16B per lane. LDS dest must be linear in tid (wave-uniform
// base + lane*16); caller guarantees &lds byte offset == tid*16 within segment.
__device__ __forceinline__ void gload16(const bf16* g, bf16* l) {
  __builtin_amdgcn_global_load_lds(
      (const __attribute__((address_space(1))) void*)g,
      (__attribute__((address_space(3))) void*)l, 16, 0, 0);
}

// ---------------- dtype detect ----------------
__global__ void detect_kernel(const unsigned* __restrict__ cosw, int* __restrict__ flag) {
  if (threadIdx.x == 0) *flag = (cosw[0] == 0x3F800000u) ? 1 : 0;
}

// ---------------- fused canonicalize: all inputs -> bf16 (+f32 resid for seg0) ----
struct CanonArgs {
  const void* src[23];
  void* dst[23];
  int n[23];  // element count (0 = skip); all counts divisible by 4
};
__global__ __launch_bounds__(256) void canon_all(CanonArgs a, float* __restrict__ resid,
                                                 const int* __restrict__ flagp) {
  const int seg = blockIdx.y;
  const int n4 = a.n[seg] >> 2;
  if (n4 == 0) return;
  const int fl = *flagp;  // wave-uniform
  if (fl) {
    const float4* s = (const float4*)a.src[seg];
    bf16* d = (bf16*)a.dst[seg];
    for (int i = blockIdx.x * 256 + threadIdx.x; i < n4; i += gridDim.x * 256) {
      float4 v = s[i];
      bf16 t[4] = {f2bf(v.x), f2bf(v.y), f2bf(v.z), f2bf(v.w)};
      *reinterpret_cast<unsigned long long*>(d + i * 4) =
          *reinterpret_cast<unsigned long long*>(t);
      if (seg == 0) *reinterpret_cast<float4*>(resid + i * 4) = v;
    }
  } else {
    const unsigned long long* s = (const unsigned long long*)a.src[seg];
    unsigned long long* d = (unsigned long long*)a.dst[seg];
    for (int i = blockIdx.x * 256 + threadIdx.x; i < n4; i += gridDim.x * 256) {
      unsigned long long v = s[i];
      d[i] = v;
      if (seg == 0) {
        const unsigned short* u = reinterpret_cast<const unsigned short*>(&v);
        float4 f;
        f.x = __uint_as_float(((unsigned)u[0]) << 16);
        f.y = __uint_as_float(((unsigned)u[1]) << 16);
        f.z = __uint_as_float(((unsigned)u[2]) << 16);
        f.w = __uint_as_float(((unsigned)u[3]) << 16);
        *reinterpret_cast<float4*>(resid + i * 4) = f;
      }
    }
  }
}

// ---------------- LayerNorm (rows of 1024, fp32 in, bf16 out) ----------------
__global__ __launch_bounds__(256) void ln_kernel(const float* __restrict__ x,
                                                 const bf16* __restrict__ g,
                                                 const bf16* __restrict__ bb,
                                                 bf16* __restrict__ y) {
  const int row = blockIdx.x;
  const float* xr = x + (size_t)row * Dm;
  const int i0 = threadIdx.x * 4;
  float4 v = *reinterpret_cast<const float4*>(xr + i0);
  float s = v.x + v.y + v.z + v.w;
  float ss = v.x * v.x + v.y * v.y + v.z * v.z + v.w * v.w;
#pragma unroll
  for (int o = 32; o > 0; o >>= 1) {
    s += __shfl_down(s, o);
    ss += __shfl_down(ss, o);
  }
  __shared__ float shs[4], shss[4];
  const int wave = threadIdx.x >> 6, lane = threadIdx.x & 63;
  if (lane == 0) { shs[wave] = s; shss[wave] = ss; }
  __syncthreads();
  s = shs[0] + shs[1] + shs[2] + shs[3];
  ss = shss[0] + shss[1] + shss[2] + shss[3];
  const float mu = s * (1.0f / Dm);
  const float var = fmaxf(ss * (1.0f / Dm) - mu * mu, 0.0f);
  const float rs = rsqrtf(var + 1e-5f);
  bf16* yr = y + (size_t)row * Dm + i0;
  float vv[4] = {v.x, v.y, v.z, v.w};
#pragma unroll
  for (int j = 0; j < 4; ++j)
    yr[j] = f2bf((vv[j] - mu) * rs * bf2f(g[i0 + j]) + bf2f(bb[i0 + j]));
}

// ---------------- GEMM 64x64 (round-2 verified; used for M=1024 kv) --------
__global__ __launch_bounds__(256) void gemm_bt(
    const bf16* __restrict__ A, const bf16* __restrict__ W,
    const bf16* __restrict__ bias, bf16* __restrict__ outB, float* __restrict__ outF,
    const float* __restrict__ residIn, float* __restrict__ residOut,
    const int* __restrict__ flagp, int M, int N, int K, int epi) {
  __shared__ bf16 As[64][40];
  __shared__ bf16 Ws[64][40];
  const int tid = threadIdx.x;
  const int m0 = blockIdx.x * 64, n0 = blockIdx.y * 64;
  const int wave = tid >> 6, lane = tid & 63;
  const int wm = wave >> 1, wn = wave & 1;
  const int quad = lane >> 4, m16 = lane & 15;
  const int lr = tid >> 2, lc = (tid & 3) * 8;

  f32x4 acc[2][2] = {};

  const bf16* Ap = A + (size_t)(m0 + lr) * K + lc;
  const bf16* Wp = W + (size_t)(n0 + lr) * K + lc;
  for (int k0 = 0; k0 < K; k0 += 32) {
    float4 av = *reinterpret_cast<const float4*>(Ap + k0);
    float4 wv = *reinterpret_cast<const float4*>(Wp + k0);
    *reinterpret_cast<float4*>(&As[lr][lc]) = av;
    *reinterpret_cast<float4*>(&Ws[lr][lc]) = wv;
    __syncthreads();
    bf16x8 aF[2], bF[2];
#pragma unroll
    for (int t = 0; t < 2; ++t) {
      aF[t] = *reinterpret_cast<const bf16x8*>(&As[wm * 32 + t * 16 + m16][quad * 8]);
      bF[t] = *reinterpret_cast<const bf16x8*>(&Ws[wn * 32 + t * 16 + m16][quad * 8]);
    }
#pragma unroll
    for (int mt = 0; mt < 2; ++mt)
#pragma unroll
      for (int nt = 0; nt < 2; ++nt)
        acc[mt][nt] = __builtin_amdgcn_mfma_f32_16x16x32_bf16(aF[mt], bF[nt], acc[mt][nt], 0, 0, 0);
    __syncthreads();
  }
  const int fl = (epi == 3) ? *flagp : 0;
#pragma unroll
  for (int mt = 0; mt < 2; ++mt) {
#pragma unroll
    for (int nt = 0; nt < 2; ++nt) {
      const int col = n0 + wn * 32 + nt * 16 + m16;
      const float bv = bf2f(bias[col]);
#pragma unroll
      for (int r = 0; r < 4; ++r) {
        const int row = m0 + wm * 32 + mt * 16 + quad * 4 + r;
        const size_t idx = (size_t)row * N + col;
        float v = acc[mt][nt][r] + bv;
        if (epi == 0) {
          outB[idx] = f2bf(v);
        } else if (epi == 1) {
          outB[idx] = f2bf(0.5f * v * (1.0f + erff(v * 0.70710678118654752f)));
        } else if (epi == 2) {
          residOut[idx] = residIn[idx] + v;
        } else {
          const float rr = residIn[idx] + v;
          if (fl) outF[idx] = rr; else outB[idx] = f2bf(rr);
        }
      }
    }
  }
}

// ---------------- GEMM 128x128: 8-wave depth-3 counted-vmcnt DMA pipeline ---
// (round-14 structure + round-19 chunk-XOR swizzle) N=1024 GEMMs + ffn2.
// Swizzle: LDS physical chunk c of row r holds GLOBAL chunk c^((r>>1)&3).
// Stage: dest linear (DMA), source column = ((tid&3)^((sr>>1)&3))*8.
// Read: physical chunk = quad ^ ((m16>>1)&3)  (lane-uniform key).
__global__ __launch_bounds__(512) void gemm128(
    const bf16* __restrict__ A, const bf16* __restrict__ W,
    const bf16* __restrict__ bias, bf16* __restrict__ outB, float* __restrict__ outF,
    const float* __restrict__ residIn, float* __restrict__ residOut,
    const int* __restrict__ flagp, int M, int N, int K, int epi) {
  __shared__ bf16 As[4][128][32];
  __shared__ bf16 Ws[4][128][32];
  const int tid = threadIdx.x;
  const int wave = tid >> 6, lane = tid & 63;
  const int wm = wave >> 1;      // 0..3 (32-row group)
  const int wn = wave & 1;       // 0..1 (64-col group)
  const int quad = lane >> 4, m16 = lane & 15;
  const int m0 = blockIdx.x * 128, n0 = blockIdx.y * 128;

  const int sr = tid >> 2;       // 0..127 (tile row)
  const int sc = (tid & 3) * 8;  // dest k-chunk (linear for DMA)
  const int gsc = (((tid & 3) ^ ((tid >> 3) & 3)) * 8);  // swizzled SOURCE chunk
  const bf16* Ap = A + (size_t)(m0 + sr) * K + gsc;
  const bf16* Wp = W + (size_t)(n0 + sr) * K + gsc;
  const int cswz = ((quad ^ ((m16 >> 1) & 3)) * 8);      // swizzled READ chunk

  f32x4 acc[2][4] = {};

#define STAGE128(T, BUF)                                   \
  {                                                        \
    const int kk_ = (T) * 32;                              \
    gload16(Ap + kk_, &As[BUF][sr][sc]);                   \
    gload16(Wp + kk_, &Ws[BUF][sr][sc]);                   \
  }

#define READS128(RB)                                                                      \
  _Pragma("unroll") for (int tt = 0; tt < 2; ++tt)                                        \
    aF[tt] = *reinterpret_cast<const bf16x8*>(&As[RB][wm * 32 + tt * 16 + m16][cswz]);    \
  _Pragma("unroll") for (int nt = 0; nt < 4; ++nt)                                        \
    bF[nt] = *reinterpret_cast<const bf16x8*>(&Ws[RB][wn * 64 + nt * 16 + m16][cswz]);

#define MFMAS128                                                                            \
  _Pragma("unroll") for (int mt = 0; mt < 2; ++mt)                                          \
  _Pragma("unroll") for (int nt = 0; nt < 4; ++nt)                                          \
    acc[mt][nt] = __builtin_amdgcn_mfma_f32_16x16x32_bf16(aF[mt], bF[nt], acc[mt][nt], 0, 0, 0);

  const int nsteps = K >> 5;  // K=1024 or 4096 -> 32 or 128 steps
  STAGE128(0, 0)
  STAGE128(1, 1)
  STAGE128(2, 2)

  int rb = 0, sb = 3;
  for (int t = 0; t < nsteps - 2; ++t) {
    asm volatile("s_waitcnt vmcnt(4)" ::: "memory");
    __builtin_amdgcn_s_barrier();
    __builtin_amdgcn_sched_barrier(0);
    bf16x8 aF[2], bF[4];
    READS128(rb)
    __builtin_amdgcn_sched_barrier(0);
    if (t + 3 < nsteps) { STAGE128(t + 3, sb) }
    __builtin_amdgcn_sched_barrier(0);
    MFMAS128
    rb = (rb + 1 == 4) ? 0 : rb + 1;
    sb = (sb + 1 == 4) ? 0 : sb + 1;
  }
  {  // t = nsteps-2: outstanding tiles {t, t+1} = 4 loads -> wait 2 = tile t
    asm volatile("s_waitcnt vmcnt(2)" ::: "memory");
    __builtin_amdgcn_s_barrier();
    __builtin_amdgcn_sched_barrier(0);
    bf16x8 aF[2], bF[4];
    READS128(rb)
    MFMAS128
    rb = (rb + 1 == 4) ? 0 : rb + 1;
  }
  {  // t = nsteps-1
    asm volatile("s_waitcnt vmcnt(0)" ::: "memory");
    __builtin_amdgcn_s_barrier();
    __builtin_amdgcn_sched_barrier(0);
    bf16x8 aF[2], bF[4];
    READS128(rb)
    MFMAS128
  }
#undef STAGE128
#undef READS128
#undef MFMAS128

  const int fl = (epi == 3) ? *flagp : 0;
  // C/D layout: col = lane&15, row = quad*4 + reg
#pragma unroll
  for (int mt = 0; mt < 2; ++mt) {
#pragma unroll
    for (int nt = 0; nt < 4; ++nt) {
      const int col = n0 + wn * 64 + nt * 16 + m16;
      const float bv = bf2f(bias[col]);
#pragma unroll
      for (int r = 0; r < 4; ++r) {
        const int row = m0 + wm * 32 + mt * 16 + quad * 4 + r;
        const size_t idx = (size_t)row * N + col;
        float v = acc[mt][nt][r] + bv;
        if (epi == 0) {
          outB[idx] = f2bf(v);
        } else if (epi == 1) {
          outB[idx] = f2bf(0.5f * v * (1.0f + erff(v * 0.70710678118654752f)));
        } else if (epi == 2) {
          residOut[idx] = residIn[idx] + v;
        } else {
          const float rr = residIn[idx] + v;
          if (fl) outF[idx] = rr; else outB[idx] = f2bf(rr);
        }
      }
    }
  }
}

// ---------------- GEMM 256x256 (BK=64, swizzled LDS) for big-N GEMMs -------
// (round-17) 8 waves, wave-tile 128x64, acc[8][4]; 2-phase counted schedule.
__global__ __launch_bounds__(512) void gemm256(
    const bf16* __restrict__ A, const bf16* __restrict__ W,
    const bf16* __restrict__ bias, bf16* __restrict__ outB,
    int M, int N, int K, int epi) {
  __shared__ bf16 Abuf[2][256 * 64];
  __shared__ bf16 Bbuf[2][256 * 64];
  const int tid = threadIdx.x;
  const int wave = tid >> 6, lane = tid & 63;
  const int wm = wave >> 2, wn = wave & 3;
  const int quad = lane >> 4, m16 = lane & 15;
  const int m0 = blockIdx.x * 256, n0 = blockIdx.y * 256;
  const int lr8 = lane >> 3, lc8 = lane & 7;
  const int gch = (lc8 ^ lr8) * 8;  // stage-side swizzled k-chunk (elements)
  const int swz = m16 & 7;          // read-side row swizzle key

  f32x4 acc[8][4] = {};

#define STAGE256(T, BUF)                                                         \
  { const int kb_ = (T) * 64 + gch;                                              \
    _Pragma("unroll") for (int i = 0; i < 4; ++i) {                              \
      const int rr = (wave * 4 + i) * 8 + lr8;                                   \
      gload16(A + (size_t)(m0 + rr) * K + kb_, &Abuf[BUF][rr * 64 + lc8 * 8]);   \
      gload16(W + (size_t)(n0 + rr) * K + kb_, &Bbuf[BUF][rr * 64 + lc8 * 8]);   \
    } }

  const int nsteps = K >> 6;  // K=1024 -> 16 steps
  STAGE256(0, 0)
  for (int t = 0; t < nsteps; ++t) {
    asm volatile("s_waitcnt vmcnt(0)" ::: "memory");
    __builtin_amdgcn_s_barrier();
    __builtin_amdgcn_sched_barrier(0);
    const int rb = t & 1;
    bf16x8 aF[2][8], bF[2][4];
#pragma unroll
    for (int kk = 0; kk < 2; ++kk) {
      const int cswz = ((quad + 4 * kk) ^ swz) * 8;
#pragma unroll
      for (int tt = 0; tt < 8; ++tt)
        aF[kk][tt] = *reinterpret_cast<const bf16x8*>(
            &Abuf[rb][(wm * 128 + tt * 16 + m16) * 64 + cswz]);
#pragma unroll
      for (int nt = 0; nt < 4; ++nt)
        bF[kk][nt] = *reinterpret_cast<const bf16x8*>(
            &Bbuf[rb][(wn * 64 + nt * 16 + m16) * 64 + cswz]);
    }
    __builtin_amdgcn_sched_barrier(0);
    if (t + 1 < nsteps) { STAGE256(t + 1, rb ^ 1) }
    __builtin_amdgcn_sched_barrier(0);
#pragma unroll
    for (int kk = 0; kk < 2; ++kk)
#pragma unroll
      for (int mt = 0; mt < 8; ++mt)
#pragma unroll
        for (int nt = 0; nt < 4; ++nt)
          acc[mt][nt] = __builtin_amdgcn_mfma_f32_16x16x32_bf16(
              aF[kk][mt], bF[kk][nt], acc[mt][nt], 0, 0, 0);
  }
#undef STAGE256

  // C/D layout: col = lane&15, row = quad*4 + reg
#pragma unroll
  for (int mt = 0; mt < 8; ++mt) {
#pragma unroll
    for (int nt = 0; nt < 4; ++nt) {
      const int col = n0 + wn * 64 + nt * 16 + m16;
      const float bv = bf2f(bias[col]);
#pragma unroll
      for (int r = 0; r < 4; ++r) {
        const int row = m0 + wm * 128 + mt * 16 + quad * 4 + r;
        const size_t idx = (size_t)row * N + col;
        float v = acc[mt][nt][r] + bv;
        outB[idx] = (epi == 1)
                        ? f2bf(0.5f * v * (1.0f + erff(v * 0.70710678118654752f)))
                        : f2bf(v);
      }
    }
  }
}

// ---------------- RoPE in-place on qkv buffer [4096, 3072] ----------------
__global__ __launch_bounds__(256) void rope_kernel(bf16* __restrict__ qkv,
                                                   const bf16* __restrict__ cosb,
                                                   const bf16* __restrict__ sinb) {
  const int idx = blockIdx.x * 256 + threadIdx.x;  // over 4096*16*32
  const int i = idx & 31;
  const int h = (idx >> 5) & 15;
  const int r = idx >> 9;
  const int s = r & (Ssz - 1);
  const float c = bf2f(cosb[s * 32 + i]);
  const float sn = bf2f(sinb[s * 32 + i]);
  bf16* base = qkv + (size_t)r * (3 * Dm) + h * 64 + 2 * i;
  float x0 = bf2f(base[0]), x1 = bf2f(base[1]);
  base[0] = f2bf(x0 * c - x1 * sn);
  base[1] = f2bf(x0 * sn + x1 * c);
  x0 = bf2f(base[Dm]); x1 = bf2f(base[Dm + 1]);
  base[Dm] = f2bf(x0 * c - x1 * sn);
  base[Dm + 1] = f2bf(x0 * sn + x1 * c);
}

// ---------------- MFMA flash attention: 8 waves, 2 complementary 128-row
// q-tiles per block (round-18 verified; causal balance, 18 kv-tiles/block).
__global__ __launch_bounds__(512) void attn_mfma(
    const bf16* __restrict__ Qb, const bf16* __restrict__ Kb, const bf16* __restrict__ Vb,
    bf16* __restrict__ Ob, int qStride, int kvStride, int kvLen, int causal, float scale) {
  __shared__ bf16 Ks[64][72];
  __shared__ bf16 Vt[64][72];
  __shared__ bf16 Ps[128][72];
  const int tid = threadIdx.x;
  const int wave = tid >> 6, lane = tid & 63;
  const int quad = lane >> 4, m16 = lane & 15;
  const int b = blockIdx.z, h = blockIdx.y;

  for (int half = 0; half < 2; ++half) {
    const int qidx = (half == 0) ? blockIdx.x : (2 * gridDim.x - 1 - blockIdx.x);
    const int q0 = qidx * 128;
    __syncthreads();  // Ps reuse guard between halves (uniform)
    {  // Q staging: 512 thr x 32B = 16KB
      const int sr = tid >> 2, sc = (tid & 3) * 16;
      const bf16* qp = Qb + (size_t)(b * Ssz + q0 + sr) * qStride + h * 64 + sc;
      float4 a = reinterpret_cast<const float4*>(qp)[0];
      float4 bb2 = reinterpret_cast<const float4*>(qp)[1];
      *reinterpret_cast<float4*>(&Ps[sr][sc]) = a;
      *reinterpret_cast<float4*>(&Ps[sr][sc + 8]) = bb2;
    }
    __syncthreads();
    bf16x8 qf[2];
    qf[0] = *reinterpret_cast<const bf16x8*>(&Ps[wave * 16 + m16][quad * 8]);
    qf[1] = *reinterpret_cast<const bf16x8*>(&Ps[wave * 16 + m16][32 + quad * 8]);

    f32x4 oacc[4] = {};
    float mrow[4], lrow[4];
#pragma unroll
    for (int r = 0; r < 4; ++r) { mrow[r] = -30000.0f; lrow[r] = 0.0f; }

    const int wrow0 = q0 + wave * 16;  // this wave's first q row
    const int nk = causal ? (q0 + 128) : kvLen;
    for (int kt = 0; kt < nk; kt += 64) {
      {  // K/V staging: row = lane, d-block = 8*wave
        const int dbase = wave * 8;
        const bf16* kp = Kb + (size_t)(b * kvLen + kt + lane) * kvStride + h * 64 + dbase;
        float4 k1 = *reinterpret_cast<const float4*>(kp);
        *reinterpret_cast<float4*>(&Ks[lane][dbase]) = k1;
        const bf16* vp = Vb + (size_t)(b * kvLen + kt + lane) * kvStride + h * 64 + dbase;
        float4 v1 = *reinterpret_cast<const float4*>(vp);
        const bf16* tv = reinterpret_cast<const bf16*>(&v1);
#pragma unroll
        for (int j = 0; j < 8; ++j) Vt[dbase + j][lane] = tv[j];
      }
      __syncthreads();

      const bool live = (causal == 0) || (kt <= wrow0 + 15);
      if (live) {
        f32x4 sacc[4] = {};
#pragma unroll
        for (int nt = 0; nt < 4; ++nt) {
          bf16x8 kf0 = *reinterpret_cast<const bf16x8*>(&Ks[nt * 16 + m16][quad * 8]);
          bf16x8 kf1 = *reinterpret_cast<const bf16x8*>(&Ks[nt * 16 + m16][32 + quad * 8]);
          sacc[nt] = __builtin_amdgcn_mfma_f32_16x16x32_bf16(qf[0], kf0, sacc[nt], 0, 0, 0);
          sacc[nt] = __builtin_amdgcn_mfma_f32_16x16x32_bf16(qf[1], kf1, sacc[nt], 0, 0, 0);
        }
        const bool dmask = (causal != 0) && (kt + 63 > wrow0);
#pragma unroll
        for (int nt = 0; nt < 4; ++nt) {
#pragma unroll
          for (int r = 0; r < 4; ++r) {
            float s = sacc[nt][r] * scale;
            if (dmask && (kt + nt * 16 + m16 > wrow0 + quad * 4 + r)) s = -30000.0f;
            sacc[nt][r] = s;
          }
        }

#pragma unroll
        for (int r = 0; r < 4; ++r) {
          float mx = fmaxf(fmaxf(sacc[0][r], sacc[1][r]), fmaxf(sacc[2][r], sacc[3][r]));
#pragma unroll
          for (int off = 1; off < 16; off <<= 1) mx = fmaxf(mx, __shfl_xor(mx, off));
          const float mn = fmaxf(mrow[r], mx);
          const float corr = __expf(mrow[r] - mn);
          mrow[r] = mn;
          float psum = 0.0f;
#pragma unroll
          for (int nt = 0; nt < 4; ++nt) {
            const float p = __expf(sacc[nt][r] - mn);
            sacc[nt][r] = p;
            psum += p;
          }
#pragma unroll
          for (int off = 1; off < 16; off <<= 1) psum += __shfl_xor(psum, off);
          lrow[r] = lrow[r] * corr + psum;
#pragma unroll
          for (int nt = 0; nt < 4; ++nt) oacc[nt][r] *= corr;
#pragma unroll
          for (int nt = 0; nt < 4; ++nt)
            Ps[wave * 16 + quad * 4 + r][nt * 16 + m16] = f2bf(sacc[nt][r]);
        }
        bf16x8 pf0 = *reinterpret_cast<const bf16x8*>(&Ps[wave * 16 + m16][quad * 8]);
        bf16x8 pf1 = *reinterpret_cast<const bf16x8*>(&Ps[wave * 16 + m16][32 + quad * 8]);
#pragma unroll
        for (int nt = 0; nt < 4; ++nt) {
          bf16x8 vf0 = *reinterpret_cast<const bf16x8*>(&Vt[nt * 16 + m16][quad * 8]);
          bf16x8 vf1 = *reinterpret_cast<const bf16x8*>(&Vt[nt * 16 + m16][32 + quad * 8]);
          oacc[nt] = __builtin_amdgcn_mfma_f32_16x16x32_bf16(pf0, vf0, oacc[nt], 0, 0, 0);
          oacc[nt] = __builtin_amdgcn_mfma_f32_16x16x32_bf16(pf1, vf1, oacc[nt], 0, 0, 0);
        }
      }
      __syncthreads();
    }

    float inv[4];
#pragma unroll
    for (int r = 0; r < 4; ++r) inv[r] = 1.0f / lrow[r];
#pragma unroll
    for (int r = 0; r < 4; ++r) {
      bf16* op = Ob + (size_t)(b * Ssz + q0 + wave * 16 + quad * 4 + r) * Dm + h * 64 + m16;
#pragma unroll
      for (int nt = 0; nt < 4; ++nt) op[nt * 16] = f2bf(oacc[nt][r] * inv[r]);
    }
  }
}

extern "C" void kernel_launch(void* const* d_in, const int* in_sizes, int n_in,
                              void* d_out, int out_size, void* d_ws, size_t ws_size,
                              hipStream_t stream) {
  char* ws = (char*)d_ws;
  int* flagp   = (int*)ws;                          // [0,1MB) control
  float* resid = (float*)(ws + (1ull << 20));       // 16MB fp32 residual
  bf16* xln    = (bf16*)(ws + (17ull << 20));       // 8MB LN output
  bf16* aout   = (bf16*)(ws + (25ull << 20));       // 8MB attn out
  bf16* big    = (bf16*)(ws + (33ull << 20));       // 32MB: qkv | qb | ffn1
  size_t off   = (65ull << 20);                     // canonical bf16 inputs

  detect_kernel<<<1, 64, 0, stream>>>((const unsigned*)d_in[3], flagp);

  CanonArgs ca;
  bf16* c[23];
  for (int i = 0; i < 23; ++i) {
    if (i == 2) { c[i] = nullptr; ca.src[i] = d_in[i]; ca.dst[i] = nullptr; ca.n[i] = 0; continue; }
    c[i] = (bf16*)(ws + off);
    const int n = in_sizes[i];
    off += ((size_t)n * 2 + 255) & ~(size_t)255;
    ca.src[i] = d_in[i];
    ca.dst[i] = c[i];
    ca.n[i] = n;
  }
  canon_all<<<dim3(256, 23), 256, 0, stream>>>(ca, resid, flagp);

  const bf16 *memory = c[1], *rope_cos = c[3], *rope_sin = c[4];
  const bf16 *qkv_w = c[5], *qkv_b = c[6], *out_w = c[7], *out_b = c[8];
  const bf16 *ca_in_w = c[9], *ca_in_b = c[10], *ca_out_w = c[11], *ca_out_b = c[12];
  const bf16 *ffn_w1 = c[13], *ffn_b1 = c[14], *ffn_w2 = c[15], *ffn_b2 = c[16];
  const bf16 *ln1_g = c[17], *ln1_b = c[18], *ln2_g = c[19], *ln2_b = c[20];
  const bf16 *ln3_g = c[21], *ln3_b = c[22];

  bf16* qb = big;
  bf16* kb = (bf16*)(ws + (41ull << 20));
  bf16* vb = (bf16*)(ws + (43ull << 20));
  bf16* outB = (bf16*)d_out;
  float* outF = (float*)d_out;

  const int ROWS = Bn * Ssz;   // 4096
  const float scale = 0.125f;  // 1/sqrt(64)

  // ---- self attention ----
  ln_kernel<<<ROWS, 256, 0, stream>>>(resid, ln1_g, ln1_b, xln);
  gemm256<<<dim3(ROWS / 256, (3 * Dm) / 256), 512, 0, stream>>>(
      xln, qkv_w, qkv_b, big, ROWS, 3 * Dm, Dm, 0);
  rope_kernel<<<(ROWS * Hh * (HDd / 2)) / 256, 256, 0, stream>>>(big, rope_cos, rope_sin);
  attn_mfma<<<dim3(Ssz / 256, Hh, Bn), 512, 0, stream>>>(
      big, big + Dm, big + 2 * Dm, aout, 3 * Dm, 3 * Dm, Ssz, 1, scale);
  gemm128<<<dim3(ROWS / 128, Dm / 128), 512, 0, stream>>>(
      aout, out_w, out_b, nullptr, nullptr, resid, resid, nullptr, ROWS, Dm, Dm, 2);

  // ---- cross attention ----
  ln_kernel<<<ROWS, 256, 0, stream>>>(resid, ln2_g, ln2_b, xln);
  gemm128<<<dim3(ROWS / 128, Dm / 128), 512, 0, stream>>>(
      xln, ca_in_w, ca_in_b, qb, nullptr, nullptr, nullptr, nullptr, ROWS, Dm, Dm, 0);
  gemm_bt<<<dim3((Bn * MEMn) / 64, Dm / 64), 256, 0, stream>>>(
      memory, ca_in_w + (size_t)Dm * Dm, ca_in_b + Dm, kb, nullptr, nullptr, nullptr, nullptr,
      Bn * MEMn, Dm, Dm, 0);
  gemm_bt<<<dim3((Bn * MEMn) / 64, Dm / 64), 256, 0, stream>>>(
      memory, ca_in_w + (size_t)2 * Dm * Dm, ca_in_b + 2 * Dm, vb, nullptr, nullptr, nullptr, nullptr,
      Bn * MEMn, Dm, Dm, 0);
  attn_mfma<<<dim3(Ssz / 256, Hh, Bn), 512, 0, stream>>>(
      qb, kb, vb, aout, Dm, Dm, MEMn, 0, scale);
  gemm128<<<dim3(ROWS / 128, Dm / 128), 512, 0, stream>>>(
      aout, ca_out_w, ca_out_b, nullptr, nullptr, resid, resid, nullptr, ROWS, Dm, Dm, 2);

  // ---- FFN ----
  ln_kernel<<<ROWS, 256, 0, stream>>>(resid, ln3_g, ln3_b, xln);
  gemm256<<<dim3(ROWS / 256, DFFn / 256), 512, 0, stream>>>(
      xln, ffn_w1, ffn_b1, big, ROWS, DFFn, Dm, 1);
  gemm128<<<dim3(ROWS / 128, Dm / 128), 512, 0, stream>>>(
      big, ffn_w2, ffn_b2, outB, outF, resid, nullptr, flagp, ROWS, Dm, DFFn, 3);
}